// Round 12
// baseline (362.748 us; speedup 1.0000x reference)
//
#include <hip/hip_runtime.h>
#include <stdint.h>

typedef _Float16 f16;
typedef _Float16 f16x8 __attribute__((ext_vector_type(8)));
typedef _Float16 f16x4 __attribute__((ext_vector_type(4)));
typedef float floatx4 __attribute__((ext_vector_type(4)));
typedef uint32_t u32x2 __attribute__((ext_vector_type(2)));

#define AS1 __attribute__((address_space(1)))
#define AS3 __attribute__((address_space(3)))

static __device__ __forceinline__ floatx4 mfma32(f16x8 a, f16x8 b, floatx4 c) {
  return __builtin_amdgcn_mfma_f32_16x16x32_f16(a, b, c, 0, 0, 0);
}
static __device__ __forceinline__ floatx4 mfma16(f16x4 a, f16x4 b, floatx4 c) {
  return __builtin_amdgcn_mfma_f32_16x16x16f16(a, b, c, 0, 0, 0);
}
static __device__ __forceinline__ uint32_t pack2(f16 lo, f16 hi) {
  return (uint32_t)__builtin_bit_cast(uint16_t, lo) |
         ((uint32_t)__builtin_bit_cast(uint16_t, hi) << 16);
}
static __device__ __forceinline__ float max3f(float a, float b, float c) {
  return fmaxf(fmaxf(a, b), c);  // fuses to v_max3_f32
}
static __device__ __forceinline__ uint32_t pkrtz(float a, float b) {
  return __builtin_bit_cast(uint32_t, __builtin_amdgcn_cvt_pkrtz(a, b));
}
// async global->LDS, 16B/lane; LDS dest is wave-uniform base + lane*16
static __device__ __forceinline__ void gload_lds16(const void* g, void* l) {
  __builtin_amdgcn_global_load_lds((AS1 void*)g, (AS3 void*)l, 16, 0, 0);
}

// raw=1: p holds fp32 (convert); raw=0: p holds f16. e = ELEMENT index.
static __device__ __forceinline__ f16x8 load8(const void* p, size_t e, int raw) {
  if (!raw) return *(const f16x8*)((const f16*)p + e);
  const float* f = (const float*)p + e;
  floatx4 a = *(const floatx4*)f, b = *(const floatx4*)(f + 4);
  f16x8 r;
  r[0] = (f16)a[0]; r[1] = (f16)a[1]; r[2] = (f16)a[2]; r[3] = (f16)a[3];
  r[4] = (f16)b[0]; r[5] = (f16)b[1]; r[6] = (f16)b[2]; r[7] = (f16)b[3];
  return r;
}
static __device__ __forceinline__ float load1(const void* p, size_t e, int raw) {
  return raw ? ((const float*)p)[e] : (float)((const f16*)p)[e];
}

// ---------------------------------------------------------------------------
__global__ __launch_bounds__(256) void cvt_f16(const float* __restrict__ src,
                                               f16* __restrict__ dst, long n8) {
  long i = (long)blockIdx.x * 256 + threadIdx.x;
  if (i >= n8) return;
  *(f16x8*)(dst + i * 8) = load8(src, (size_t)i * 8, 1);
}

// ---------------------------------------------------------------------------
// transpose_group: heads [g0,g0+G) of Wqkv (48,1024,64) fp32 -> Wt (N,1024)
// f16 rows [q.. k.. v.. pad]; Q-sections pre-scaled by 8 (folds score scale).
// ---------------------------------------------------------------------------
__global__ __launch_bounds__(256) void transpose_group(const float* __restrict__ W,
                                                       const float* __restrict__ bq,
                                                       f16* __restrict__ Wt,
                                                       f16* __restrict__ biasc,
                                                       int g0, int G) {
  __shared__ f16 T[64 * 80];
  const int s = blockIdx.x;
  const int d0 = blockIdx.y * 64;
  const int tid = threadIdx.x;
  if (s >= 3 * G) {
#pragma unroll
    for (int st = 0; st < 2; ++st) {
      int j = tid + st * 256;
      int hh = j >> 3, dc = j & 7;
      f16x8 z = {};
      *(f16x8*)&Wt[(size_t)(s * 64 + hh) * 1024 + d0 + dc * 8] = z;
    }
    if (blockIdx.y == 0 && tid < 64) biasc[s * 64 + tid] = (f16)0.f;
    return;
  }
  const int e = (s / G) * 16 + g0 + (s % G);
  const float scale = (s < G) ? 8.f : 1.f;
#pragma unroll
  for (int st = 0; st < 2; ++st) {
    int j = tid + st * 256;
    int dl = j >> 3, hc = j & 7;
    const float* f = &W[((size_t)e * 1024 + d0 + dl) * 64 + hc * 8];
#pragma unroll
    for (int jj = 0; jj < 8; ++jj) T[(hc * 8 + jj) * 80 + dl] = (f16)(f[jj] * scale);
  }
  __syncthreads();
#pragma unroll
  for (int st = 0; st < 2; ++st) {
    int j = tid + st * 256;
    int hh = j >> 3, dc = j & 7;
    f16x8 o = *(const f16x8*)&T[hh * 80 + dc * 8];
    *(f16x8*)&Wt[(size_t)(s * 64 + hh) * 1024 + d0 + dc * 8] = o;
  }
  if (blockIdx.y == 0 && tid < 64)
    biasc[s * 64 + tid] = (f16)(bq[(size_t)e * 64 + tid] * scale);
}

// ---------------------------------------------------------------------------
// GEMM C = A @ B^T + bias. 128x128 tile, BK=64. XCD-swizzled block mapping
// (8 y-rows per XCD slab) when gridDim.y % 8 == 0.
// ---------------------------------------------------------------------------
template <int AASYNC, int BASYNC>
__global__ __launch_bounds__(256) void gemm_bt(const void* __restrict__ A, size_t a0,
                                               int aRaw, const void* __restrict__ B,
                                               int bRaw, const void* __restrict__ bias,
                                               int biasRaw, void* __restrict__ C,
                                               size_t c0, int cHalf,
                                               int M, int N, int K, int ldc) {
  constexpr int AST = AASYNC ? 64 : 72;
  constexpr int BST = BASYNC ? 64 : 72;
  __shared__ f16 As[128 * AST];
  __shared__ f16 Bs[128 * BST];
  const int tid = threadIdx.x;
  const int wave = tid >> 6, lane = tid & 63;
  const int c = lane & 15, g = lane >> 4;

  int bx = blockIdx.x, by = blockIdx.y;
  {
    int gx = gridDim.x, gy = gridDim.y;
    if ((gy & 7) == 0) {  // XCD (~bid%8) gets an 8-row y-slab: A slab + B reuse in L2
      int bid = by * gx + bx;
      int local = bid >> 3, ypg = gy >> 3;
      bx = local % gx;
      by = (bid & 7) * ypg + local / gx;
    }
  }
  const int bm = by * 128, bn = bx * 128;
  const int wm = (wave >> 1) * 64, wn = (wave & 1) * 64;

  floatx4 acc[4][4] = {};

  for (int k0 = 0; k0 < K; k0 += 64) {
    if (AASYNC) {
      const f16* Af = (const f16*)A;
#pragma unroll
      for (int t = 0; t < 4; ++t) {
        int j = (wave * 4 + t) * 64 + lane;
        int row = j >> 3;
        int kc = (j & 7) ^ (row & 7);
        gload_lds16(Af + a0 + (size_t)(bm + row) * K + k0 + kc * 8,
                    As + (wave * 4 + t) * 512);
      }
    } else {
#pragma unroll
      for (int s = 0; s < 4; ++s) {
        int j = tid + s * 256;
        int row = j >> 3, ch = j & 7;
        *(f16x8*)&As[row * 72 + ch * 8] =
            load8(A, a0 + (size_t)(bm + row) * K + k0 + ch * 8, aRaw);
      }
    }
    if (BASYNC) {
      const f16* Bf = (const f16*)B;
#pragma unroll
      for (int t = 0; t < 4; ++t) {
        int j = (wave * 4 + t) * 64 + lane;
        int row = j >> 3;
        int kc = (j & 7) ^ (row & 7);
        gload_lds16(Bf + (size_t)(bn + row) * K + k0 + kc * 8,
                    Bs + (wave * 4 + t) * 512);
      }
    } else {
#pragma unroll
      for (int s = 0; s < 4; ++s) {
        int j = tid + s * 256;
        int row = j >> 3, ch = j & 7;
        *(f16x8*)&Bs[row * 72 + ch * 8] =
            load8(B, (size_t)(bn + row) * K + k0 + ch * 8, bRaw);
      }
    }
    __syncthreads();
#pragma unroll
    for (int kk = 0; kk < 2; ++kk) {
      f16x8 af[4], bfr[4];
#pragma unroll
      for (int i = 0; i < 4; ++i) {
        int ar = wm + i * 16 + c;
        int apos = AASYNC ? ((kk * 4 + g) ^ (ar & 7)) : (kk * 4 + g);
        af[i] = *(const f16x8*)&As[ar * AST + apos * 8];
        int br = wn + i * 16 + c;
        int bpos = BASYNC ? ((kk * 4 + g) ^ (br & 7)) : (kk * 4 + g);
        bfr[i] = *(const f16x8*)&Bs[br * BST + bpos * 8];
      }
#pragma unroll
      for (int i = 0; i < 4; ++i)
#pragma unroll
        for (int jn = 0; jn < 4; ++jn)
          acc[i][jn] = mfma32(af[i], bfr[jn], acc[i][jn]);
    }
    __syncthreads();
  }

  float bv[4];
#pragma unroll
  for (int jn = 0; jn < 4; ++jn)
    bv[jn] = load1(bias, (size_t)(bn + wn + jn * 16 + c), biasRaw);
#pragma unroll
  for (int i = 0; i < 4; ++i) {
#pragma unroll
    for (int r = 0; r < 4; ++r) {
      size_t row = (size_t)(bm + wm + i * 16 + g * 4 + r);
#pragma unroll
      for (int jn = 0; jn < 4; ++jn) {
        float v = acc[i][jn][r] + bv[jn];
        size_t idx = c0 + row * ldc + (bn + wn + jn * 16 + c);
        if (cHalf) ((f16*)C)[idx] = (f16)v; else ((float*)C)[idx] = v;
      }
    }
  }
}

// ---------------------------------------------------------------------------
// Flash attention, S^T form. 128 q-rows/block (4 waves x 2 strips).
// Q pre-scaled by 8. K staged ASYNC (global_load_lds, XOR-swizzled [64][64]);
// V staged transposed as packed kv-pair dwords. Softmax: max3 tree + 2
// shuffles, exp via fma+exp2, P packed via cvt_pkrtz, l via in-lane adds.
// Natural VGPR (plain launch_bounds): R10 showed >128 VGPR halves occupancy;
// R11 showed forcing 64 VGPR adds remat instructions. Grid gives 4 blocks/CU,
// so 104-128 VGPR (4 waves/SIMD) is the sweet spot.
// Head<->x remap: each XCD owns 2 heads' K/V (L2-resident; FETCH 139->25MB).
// ---------------------------------------------------------------------------
__global__ __launch_bounds__(256) void attn_kernel(const f16* __restrict__ qkv,
                                                   f16* __restrict__ av,
                                                   int ld, int kbase, int vbase,
                                                   int gh0, int b0) {
  int hh = blockIdx.y, qi = blockIdx.x;
  if (gridDim.x == 16 && gridDim.y == 16) {  // XCD=x%8 -> heads {2k,2k+1}
    hh = (blockIdx.x & 7) * 2 + (blockIdx.x >> 3);
    qi = blockIdx.y;
  }
  const int z = blockIdx.z;
  const int q0 = qi * 128;
  const f16* base = qkv + (size_t)z * 2048 * ld;
  const f16* Qp = base + hh * 64;
  const f16* Kp = base + kbase + hh * 64;
  const f16* Vp = base + vbase + hh * 64;

  __shared__ __align__(16) char smem[18432];
  f16* Ks = (f16*)smem;                      // [64][64] kv x d, XOR-swizzled
  uint32_t* Vs = (uint32_t*)(smem + 8192);   // [64][34] d x packed kv-pairs

  const int tid = threadIdx.x;
  const int wave = tid >> 6, lane = tid & 63;
  const int c = lane & 15, g = lane >> 4;

  f16x8 qf[2][2];
#pragma unroll
  for (int st = 0; st < 2; ++st) {
    const f16* qrow = Qp + (size_t)(q0 + wave * 32 + st * 16 + c) * ld;
    qf[st][0] = *(const f16x8*)(qrow + g * 8);
    qf[st][1] = *(const f16x8*)(qrow + 32 + g * 8);
  }

  float m_i[2] = {-1e30f, -1e30f}, l_i[2] = {0.f, 0.f};
  floatx4 acc_o[2][4] = {};

  const int vp = tid & 31, vch = tid >> 5;
  const float L2E = 1.44269504f;

  for (int t = 0; t < 32; ++t) {
    const int kv0 = t * 64;
    // K: async 16B/lane into swizzled [64][64] (512 chunks over 2 iters)
#pragma unroll
    for (int it = 0; it < 2; ++it) {
      int j = (wave * 2 + it) * 64 + lane;
      int row = j >> 3;
      int kc = (j & 7) ^ (row & 7);
      gload_lds16(Kp + (size_t)(kv0 + row) * ld + kc * 8, Ks + (wave * 2 + it) * 512);
    }
    // V: transposed packed pairs
    {
      const f16* ra = Vp + (size_t)(kv0 + 2 * vp) * ld + vch * 8;
      f16x8 a = *(const f16x8*)ra;
      f16x8 bvv = *(const f16x8*)(ra + ld);
#pragma unroll
      for (int jj = 0; jj < 8; ++jj)
        Vs[(vch * 8 + jj) * 34 + vp] = pack2(a[jj], bvv[jj]);
    }
    __syncthreads();

    f16x8 kf[4][2];
#pragma unroll
    for (int nb = 0; nb < 4; ++nb)
#pragma unroll
      for (int kk = 0; kk < 2; ++kk)
        kf[nb][kk] = *(const f16x8*)&Ks[(nb * 16 + c) * 64 + ((kk * 4 + g) ^ (c & 7)) * 8];

    f16x4 pfrag[2][4];
#pragma unroll
    for (int st = 0; st < 2; ++st) {
      floatx4 sacc[4] = {};
#pragma unroll
      for (int kk = 0; kk < 2; ++kk)
#pragma unroll
        for (int nb = 0; nb < 4; ++nb)
          sacc[nb] = mfma32(kf[nb][kk], qf[st][kk], sacc[nb]);

      // max via v_max3 tree (8 ops) + 2 shuffles
      float a0 = max3f(sacc[0][0], sacc[0][1], sacc[0][2]);
      float a1 = max3f(sacc[0][3], sacc[1][0], sacc[1][1]);
      float a2 = max3f(sacc[1][2], sacc[1][3], sacc[2][0]);
      float a3 = max3f(sacc[2][1], sacc[2][2], sacc[2][3]);
      float a4 = max3f(sacc[3][0], sacc[3][1], sacc[3][2]);
      float b0 = max3f(a0, a1, sacc[3][3]);
      float b1 = max3f(a2, a3, a4);
      float mx = fmaxf(b0, b1);
      mx = fmaxf(mx, __shfl_xor(mx, 16, 64));
      mx = fmaxf(mx, __shfl_xor(mx, 32, 64));
      float mnew = fmaxf(m_i[st], mx);
      float nm = -mnew * L2E;
      float alpha = exp2f(fmaf(m_i[st], L2E, nm));
      m_i[st] = mnew;
      float rs = 0.f;
#pragma unroll
      for (int nb = 0; nb < 4; ++nb)
#pragma unroll
        for (int r = 0; r < 4; ++r) {
          sacc[nb][r] = exp2f(fmaf(sacc[nb][r], L2E, nm));
          rs += sacc[nb][r];
        }
      rs += __shfl_xor(rs, 16, 64);
      rs += __shfl_xor(rs, 32, 64);
      l_i[st] = l_i[st] * alpha + rs;
#pragma unroll
      for (int db = 0; db < 4; ++db) acc_o[st][db] *= alpha;
#pragma unroll
      for (int nb = 0; nb < 4; ++nb) {
        u32x2 w = {pkrtz(sacc[nb][0], sacc[nb][1]), pkrtz(sacc[nb][2], sacc[nb][3])};
        pfrag[st][nb] = __builtin_bit_cast(f16x4, w);
      }
    }

    // O^T += V^T @ P^T  (A-frag b64 from packed Vs; B-frag in registers)
#pragma unroll
    for (int nb = 0; nb < 4; ++nb)
#pragma unroll
      for (int db = 0; db < 4; ++db) {
        u32x2 raw = *(const u32x2*)&Vs[(db * 16 + c) * 34 + nb * 8 + 2 * g];
        f16x4 vf = __builtin_bit_cast(f16x4, raw);
#pragma unroll
        for (int st = 0; st < 2; ++st)
          acc_o[st][db] = mfma16(vf, pfrag[st][nb], acc_o[st][db]);
      }
    __syncthreads();
  }

  float inv[2] = {1.0f / l_i[0], 1.0f / l_i[1]};

  f16* Ot = (f16*)smem;  // [128][72]
#pragma unroll
  for (int st = 0; st < 2; ++st)
#pragma unroll
    for (int db = 0; db < 4; ++db)
#pragma unroll
      for (int r = 0; r < 4; ++r)
        Ot[(wave * 32 + st * 16 + c) * 72 + db * 16 + g * 4 + r] =
            (f16)(acc_o[st][db][r] * inv[st]);
  __syncthreads();
#pragma unroll
  for (int it = 0; it < 4; ++it) {
    int j = tid + it * 256;
    int row = j >> 3, ch = j & 7;
    *(f16x8*)&av[(size_t)((b0 + z) * 2048 + q0 + row) * 1024 + (gh0 + hh) * 64 + ch * 8] =
        *(const f16x8*)&Ot[row * 72 + ch * 8];
  }
}

__global__ __launch_bounds__(256) void copyk(const f16* __restrict__ src,
                                             f16* __restrict__ dst, long n8) {
  long i = (long)blockIdx.x * 256 + threadIdx.x;
  if (i < n8) ((f16x8*)dst)[i] = ((const f16x8*)src)[i];
}

// ---------------------------------------------------------------------------
extern "C" void kernel_launch(void* const* d_in, const int* in_sizes, int n_in,
                              void* d_out, int out_size, void* d_ws, size_t ws_size,
                              hipStream_t stream) {
  (void)in_sizes; (void)n_in; (void)out_size;
  const float* x    = (const float*)d_in[0];  // (4,2048,1024) fp32
  const float* Wqkv = (const float*)d_in[1];  // (48,1024,64)  fp32
  const float* bqkv = (const float*)d_in[2];  // (48,64)       fp32
  const float* Wp   = (const float*)d_in[3];  // (1024,1024)   fp32 [N][K]
  const float* bp   = (const float*)d_in[4];  // (1024,)       fp32
  float* out = (float*)d_out;                 // (4,2048,1024) fp32
  char* ws = (char*)d_ws;
  const size_t avail = ws_size;

  if (avail >= (size_t)67108864) {
    // ---- Tier A. d_out borrows: Wqkvt 6.29MB | biasc | xh 16.8MB (consumed
    // by gemm1). Wpf goes into the qkv ws region AFTER attn (qkv dead then).
    f16* Wqkvt = (f16*)d_out;
    f16* biasc = (f16*)((char*)d_out + 6291456);
    f16* xh    = (f16*)((char*)d_out + 6297600);
    f16* qkv = (f16*)ws;                    // 8192x3072 f16 (50.3MB)
    f16* av  = (f16*)(ws + 50331648);       // 8192x1024 f16 (16.8MB)
    f16* Wpf = (f16*)ws;                    // 1024x1024 f16 (2MB, aliases dead qkv)
    cvt_f16<<<dim3(4096), 256, 0, stream>>>(x, xh, 1048576);
    transpose_group<<<dim3(48, 16), 256, 0, stream>>>(Wqkv, bqkv, Wqkvt, biasc, 0, 16);
    gemm_bt<1, 1><<<dim3(24, 64), 256, 0, stream>>>(xh, 0, 0, Wqkvt, 0, biasc, 0,
                                                    qkv, 0, 1, 8192, 3072, 1024, 3072);
    attn_kernel<<<dim3(16, 16, 4), 256, 0, stream>>>(qkv, av, 3072, 1024, 2048, 0, 0);
    cvt_f16<<<dim3(512), 256, 0, stream>>>(Wp, Wpf, 131072);
    gemm_bt<1, 1><<<dim3(8, 64), 256, 0, stream>>>(av, 0, 0, Wpf, 0, bp, 1,
                                                   out, 0, 0, 8192, 1024, 1024, 1024);
    return;
  }

  // ---- Head-group tiers (legacy staging): av (f16) in d_out; projection
  // reverse-chunked (in-place safe under fp32 2x widening).
  auto need = [](size_t N, size_t Mr) { return N * 2 * (1024 + Mr + 1); };
  int G; bool perBatch = false;
  if      (avail >= need(3072, 8192)) G = 16;
  else if (avail >= need(1536, 8192)) G = 8;
  else if (avail >= need(768, 8192))  G = 4;
  else if (avail >= need(384, 8192))  G = 2;
  else if (avail >= need(256, 8192))  G = 1;
  else { G = 1; perBatch = true; }
  const int N = (G == 1) ? 256 : G * 192;
  const size_t Mr = perBatch ? 2048 : 8192;

  f16* Wt    = (f16*)ws;                                        // N x 1024
  f16* qkvg  = (f16*)(ws + (size_t)N * 1024 * 2);               // Mr x N
  f16* biasc = (f16*)(ws + (size_t)N * 1024 * 2 + Mr * N * 2);  // N
  f16* av    = (f16*)d_out;
  const int tgrid = 3 * G + (G == 1 ? 1 : 0);

  for (int g0 = 0; g0 < 16; g0 += G) {
    transpose_group<<<dim3(tgrid, 16), 256, 0, stream>>>(Wqkv, bqkv, Wt, biasc, g0, G);
    if (!perBatch) {
      gemm_bt<0, 0><<<dim3(N / 128, 64), 256, 0, stream>>>(x, 0, 1, Wt, 0, biasc, 0,
                                                           qkvg, 0, 1, 8192, N, 1024, N);
      attn_kernel<<<dim3(16, G, 4), 256, 0, stream>>>(qkvg, av, N, G * 64, 2 * G * 64, g0, 0);
    } else {
      for (int b = 0; b < 4; ++b) {
        gemm_bt<0, 0><<<dim3(N / 128, 16), 256, 0, stream>>>(x, (size_t)b * 2048 * 1024, 1,
                                                             Wt, 0, biasc, 0, qkvg, 0, 1,
                                                             2048, N, 1024, N);
        attn_kernel<<<dim3(16, G, 1), 256, 0, stream>>>(qkvg, av, N, G * 64, 2 * G * 64, g0, b);
      }
    }
  }

  f16* chunkbuf = qkvg;
  const int rows = perBatch ? 512 : 1024;
  for (int r0 = 8192 - rows; r0 >= 0; r0 -= rows) {
    long n8 = (long)rows * 1024 / 8;
    copyk<<<dim3((int)(n8 / 256)), 256, 0, stream>>>(av + (size_t)r0 * 1024, chunkbuf, n8);
    gemm_bt<0, 0><<<dim3(8, rows / 128), 256, 0, stream>>>(chunkbuf, 0, 0, Wp, 1, bp, 1,
                                                           out, (size_t)r0 * 1024, 0,
                                                           rows, 1024, 1024, 1024);
  }
}

// Round 13
// 332.701 us; speedup vs baseline: 1.0903x; 1.0903x over previous
//
#include <hip/hip_runtime.h>
#include <stdint.h>

typedef _Float16 f16;
typedef _Float16 f16x8 __attribute__((ext_vector_type(8)));
typedef _Float16 f16x4 __attribute__((ext_vector_type(4)));
typedef float floatx4 __attribute__((ext_vector_type(4)));
typedef uint32_t u32x2 __attribute__((ext_vector_type(2)));

#define AS1 __attribute__((address_space(1)))
#define AS3 __attribute__((address_space(3)))

static __device__ __forceinline__ floatx4 mfma32(f16x8 a, f16x8 b, floatx4 c) {
  return __builtin_amdgcn_mfma_f32_16x16x32_f16(a, b, c, 0, 0, 0);
}
static __device__ __forceinline__ floatx4 mfma16(f16x4 a, f16x4 b, floatx4 c) {
  return __builtin_amdgcn_mfma_f32_16x16x16f16(a, b, c, 0, 0, 0);
}
static __device__ __forceinline__ uint32_t pack2(f16 lo, f16 hi) {
  return (uint32_t)__builtin_bit_cast(uint16_t, lo) |
         ((uint32_t)__builtin_bit_cast(uint16_t, hi) << 16);
}
// async global->LDS, 16B/lane; LDS dest is wave-uniform base + lane*16
static __device__ __forceinline__ void gload_lds16(const void* g, void* l) {
  __builtin_amdgcn_global_load_lds((AS1 void*)g, (AS3 void*)l, 16, 0, 0);
}

// raw=1: p holds fp32 (convert); raw=0: p holds f16. e = ELEMENT index.
static __device__ __forceinline__ f16x8 load8(const void* p, size_t e, int raw) {
  if (!raw) return *(const f16x8*)((const f16*)p + e);
  const float* f = (const float*)p + e;
  floatx4 a = *(const floatx4*)f, b = *(const floatx4*)(f + 4);
  f16x8 r;
  r[0] = (f16)a[0]; r[1] = (f16)a[1]; r[2] = (f16)a[2]; r[3] = (f16)a[3];
  r[4] = (f16)b[0]; r[5] = (f16)b[1]; r[6] = (f16)b[2]; r[7] = (f16)b[3];
  return r;
}
static __device__ __forceinline__ float load1(const void* p, size_t e, int raw) {
  return raw ? ((const float*)p)[e] : (float)((const f16*)p)[e];
}

// ---------------------------------------------------------------------------
__global__ __launch_bounds__(256) void cvt_f16(const float* __restrict__ src,
                                               f16* __restrict__ dst, long n8) {
  long i = (long)blockIdx.x * 256 + threadIdx.x;
  if (i >= n8) return;
  *(f16x8*)(dst + i * 8) = load8(src, (size_t)i * 8, 1);
}

// ---------------------------------------------------------------------------
// transpose_group: heads [g0,g0+G) of Wqkv (48,1024,64) fp32 -> Wt (N,1024)
// f16 rows [q.. k.. v.. pad]; Q-sections pre-scaled by 8 (folds score scale).
// ---------------------------------------------------------------------------
__global__ __launch_bounds__(256) void transpose_group(const float* __restrict__ W,
                                                       const float* __restrict__ bq,
                                                       f16* __restrict__ Wt,
                                                       f16* __restrict__ biasc,
                                                       int g0, int G) {
  __shared__ f16 T[64 * 80];
  const int s = blockIdx.x;
  const int d0 = blockIdx.y * 64;
  const int tid = threadIdx.x;
  if (s >= 3 * G) {
#pragma unroll
    for (int st = 0; st < 2; ++st) {
      int j = tid + st * 256;
      int hh = j >> 3, dc = j & 7;
      f16x8 z = {};
      *(f16x8*)&Wt[(size_t)(s * 64 + hh) * 1024 + d0 + dc * 8] = z;
    }
    if (blockIdx.y == 0 && tid < 64) biasc[s * 64 + tid] = (f16)0.f;
    return;
  }
  const int e = (s / G) * 16 + g0 + (s % G);
  const float scale = (s < G) ? 8.f : 1.f;
#pragma unroll
  for (int st = 0; st < 2; ++st) {
    int j = tid + st * 256;
    int dl = j >> 3, hc = j & 7;
    const float* f = &W[((size_t)e * 1024 + d0 + dl) * 64 + hc * 8];
#pragma unroll
    for (int jj = 0; jj < 8; ++jj) T[(hc * 8 + jj) * 80 + dl] = (f16)(f[jj] * scale);
  }
  __syncthreads();
#pragma unroll
  for (int st = 0; st < 2; ++st) {
    int j = tid + st * 256;
    int hh = j >> 3, dc = j & 7;
    f16x8 o = *(const f16x8*)&T[hh * 80 + dc * 8];
    *(f16x8*)&Wt[(size_t)(s * 64 + hh) * 1024 + d0 + dc * 8] = o;
  }
  if (blockIdx.y == 0 && tid < 64)
    biasc[s * 64 + tid] = (f16)(bq[(size_t)e * 64 + tid] * scale);
}

// ---------------------------------------------------------------------------
// GEMM C = A @ B^T + bias. 128x128 tile, BK=64. XCD-swizzled block mapping
// (8 y-rows per XCD slab) when gridDim.y % 8 == 0.
// ---------------------------------------------------------------------------
template <int AASYNC, int BASYNC>
__global__ __launch_bounds__(256) void gemm_bt(const void* __restrict__ A, size_t a0,
                                               int aRaw, const void* __restrict__ B,
                                               int bRaw, const void* __restrict__ bias,
                                               int biasRaw, void* __restrict__ C,
                                               size_t c0, int cHalf,
                                               int M, int N, int K, int ldc) {
  constexpr int AST = AASYNC ? 64 : 72;
  constexpr int BST = BASYNC ? 64 : 72;
  __shared__ f16 As[128 * AST];
  __shared__ f16 Bs[128 * BST];
  const int tid = threadIdx.x;
  const int wave = tid >> 6, lane = tid & 63;
  const int c = lane & 15, g = lane >> 4;

  int bx = blockIdx.x, by = blockIdx.y;
  {
    int gx = gridDim.x, gy = gridDim.y;
    if ((gy & 7) == 0) {  // XCD (~bid%8) gets an 8-row y-slab: A slab + B reuse in L2
      int bid = by * gx + bx;
      int local = bid >> 3, ypg = gy >> 3;
      bx = local % gx;
      by = (bid & 7) * ypg + local / gx;
    }
  }
  const int bm = by * 128, bn = bx * 128;
  const int wm = (wave >> 1) * 64, wn = (wave & 1) * 64;

  floatx4 acc[4][4] = {};

  for (int k0 = 0; k0 < K; k0 += 64) {
    if (AASYNC) {
      const f16* Af = (const f16*)A;
#pragma unroll
      for (int t = 0; t < 4; ++t) {
        int j = (wave * 4 + t) * 64 + lane;
        int row = j >> 3;
        int kc = (j & 7) ^ (row & 7);
        gload_lds16(Af + a0 + (size_t)(bm + row) * K + k0 + kc * 8,
                    As + (wave * 4 + t) * 512);
      }
    } else {
#pragma unroll
      for (int s = 0; s < 4; ++s) {
        int j = tid + s * 256;
        int row = j >> 3, ch = j & 7;
        *(f16x8*)&As[row * 72 + ch * 8] =
            load8(A, a0 + (size_t)(bm + row) * K + k0 + ch * 8, aRaw);
      }
    }
    if (BASYNC) {
      const f16* Bf = (const f16*)B;
#pragma unroll
      for (int t = 0; t < 4; ++t) {
        int j = (wave * 4 + t) * 64 + lane;
        int row = j >> 3;
        int kc = (j & 7) ^ (row & 7);
        gload_lds16(Bf + (size_t)(bn + row) * K + k0 + kc * 8,
                    Bs + (wave * 4 + t) * 512);
      }
    } else {
#pragma unroll
      for (int s = 0; s < 4; ++s) {
        int j = tid + s * 256;
        int row = j >> 3, ch = j & 7;
        *(f16x8*)&Bs[row * 72 + ch * 8] =
            load8(B, (size_t)(bn + row) * K + k0 + ch * 8, bRaw);
      }
    }
    __syncthreads();
#pragma unroll
    for (int kk = 0; kk < 2; ++kk) {
      f16x8 af[4], bfr[4];
#pragma unroll
      for (int i = 0; i < 4; ++i) {
        int ar = wm + i * 16 + c;
        int apos = AASYNC ? ((kk * 4 + g) ^ (ar & 7)) : (kk * 4 + g);
        af[i] = *(const f16x8*)&As[ar * AST + apos * 8];
        int br = wn + i * 16 + c;
        int bpos = BASYNC ? ((kk * 4 + g) ^ (br & 7)) : (kk * 4 + g);
        bfr[i] = *(const f16x8*)&Bs[br * BST + bpos * 8];
      }
#pragma unroll
      for (int i = 0; i < 4; ++i)
#pragma unroll
        for (int jn = 0; jn < 4; ++jn)
          acc[i][jn] = mfma32(af[i], bfr[jn], acc[i][jn]);
    }
    __syncthreads();
  }

  float bv[4];
#pragma unroll
  for (int jn = 0; jn < 4; ++jn)
    bv[jn] = load1(bias, (size_t)(bn + wn + jn * 16 + c), biasRaw);
#pragma unroll
  for (int i = 0; i < 4; ++i) {
#pragma unroll
    for (int r = 0; r < 4; ++r) {
      size_t row = (size_t)(bm + wm + i * 16 + g * 4 + r);
#pragma unroll
      for (int jn = 0; jn < 4; ++jn) {
        float v = acc[i][jn][r] + bv[jn];
        size_t idx = c0 + row * ldc + (bn + wn + jn * 16 + c);
        if (cHalf) ((f16*)C)[idx] = (f16)v; else ((float*)C)[idx] = v;
      }
    }
  }
}

// ---------------------------------------------------------------------------
// Flash attention, S^T form — VERBATIM the R8 kernel (measured best: 152us,
// VGPR 104) plus ONLY the XCD head<->x remap (FETCH 139->25MB, verified
// R10-R12). R10-R12 taught: max3/exp2-fma/pkrtz/async-K trims all regressed
// via VGPR/codegen side-effects on this issue-bound kernel. Do not re-add
// without isolating.
// ---------------------------------------------------------------------------
__global__ __launch_bounds__(256) void attn_kernel(const f16* __restrict__ qkv,
                                                   f16* __restrict__ av,
                                                   int ld, int kbase, int vbase,
                                                   int gh0, int b0) {
  int hh = blockIdx.y, qi = blockIdx.x;
  if (gridDim.x == 16 && gridDim.y == 16) {  // XCD=x%8 -> heads {2k,2k+1}
    hh = (blockIdx.x & 7) * 2 + (blockIdx.x >> 3);
    qi = blockIdx.y;
  }
  const int z = blockIdx.z;
  const int q0 = qi * 128;
  const f16* base = qkv + (size_t)z * 2048 * ld;
  const f16* Qp = base + hh * 64;
  const f16* Kp = base + kbase + hh * 64;
  const f16* Vp = base + vbase + hh * 64;

  __shared__ __align__(16) char smem[18432];
  f16* Ks = (f16*)smem;                      // [64][72] kv x d
  uint32_t* Vs = (uint32_t*)(smem + 9216);   // [64][34] d x packed kv-pairs

  const int tid = threadIdx.x;
  const int wave = tid >> 6, lane = tid & 63;
  const int c = lane & 15, g = lane >> 4;

  f16x8 qf[2][2];
#pragma unroll
  for (int st = 0; st < 2; ++st) {
    const f16* qrow = Qp + (size_t)(q0 + wave * 32 + st * 16 + c) * ld;
    qf[st][0] = *(const f16x8*)(qrow + g * 8);
    qf[st][1] = *(const f16x8*)(qrow + 32 + g * 8);
  }

  float m_i[2] = {-1e30f, -1e30f}, l_i[2] = {0.f, 0.f};
  floatx4 acc_o[2][4] = {};

  const int vp = tid & 31, vch = tid >> 5;
  const float L2E = 1.44269504f;
  (void)L2E;

  for (int t = 0; t < 32; ++t) {
    const int kv0 = t * 64;
#pragma unroll
    for (int it = 0; it < 2; ++it) {
      int j = tid + it * 256;
      int row = j >> 3, ch = j & 7;
      *(f16x8*)&Ks[row * 72 + ch * 8] =
          *(const f16x8*)(Kp + (size_t)(kv0 + row) * ld + ch * 8);
    }
    {
      const f16* ra = Vp + (size_t)(kv0 + 2 * vp) * ld + vch * 8;
      f16x8 a = *(const f16x8*)ra;
      f16x8 bvv = *(const f16x8*)(ra + ld);
#pragma unroll
      for (int jj = 0; jj < 8; ++jj)
        Vs[(vch * 8 + jj) * 34 + vp] = pack2(a[jj], bvv[jj]);
    }
    __syncthreads();

    f16x8 kf[4][2];
#pragma unroll
    for (int nb = 0; nb < 4; ++nb)
#pragma unroll
      for (int kk = 0; kk < 2; ++kk)
        kf[nb][kk] = *(const f16x8*)&Ks[(nb * 16 + c) * 72 + (kk * 4 + g) * 8];

    f16x4 pfrag[2][4];
#pragma unroll
    for (int st = 0; st < 2; ++st) {
      floatx4 sacc[4] = {};
#pragma unroll
      for (int kk = 0; kk < 2; ++kk)
#pragma unroll
        for (int nb = 0; nb < 4; ++nb)
          sacc[nb] = mfma32(kf[nb][kk], qf[st][kk], sacc[nb]);

      float sv[4][4];
      float mx = -1e30f;
#pragma unroll
      for (int nb = 0; nb < 4; ++nb)
#pragma unroll
        for (int r = 0; r < 4; ++r) {
          sv[nb][r] = sacc[nb][r];
          mx = fmaxf(mx, sv[nb][r]);
        }
      mx = fmaxf(mx, __shfl_xor(mx, 16, 64));
      mx = fmaxf(mx, __shfl_xor(mx, 32, 64));
      float mnew = fmaxf(m_i[st], mx);
      float alpha = __expf(m_i[st] - mnew);
      float rs = 0.f;
#pragma unroll
      for (int nb = 0; nb < 4; ++nb)
#pragma unroll
        for (int r = 0; r < 4; ++r) {
          sv[nb][r] = __expf(sv[nb][r] - mnew);
          rs += sv[nb][r];
        }
      rs += __shfl_xor(rs, 16, 64);
      rs += __shfl_xor(rs, 32, 64);
      m_i[st] = mnew;
      l_i[st] = l_i[st] * alpha + rs;
#pragma unroll
      for (int db = 0; db < 4; ++db) acc_o[st][db] *= alpha;
#pragma unroll
      for (int nb = 0; nb < 4; ++nb) {
        f16x4 pf = {(f16)sv[nb][0], (f16)sv[nb][1], (f16)sv[nb][2], (f16)sv[nb][3]};
        pfrag[st][nb] = pf;
      }
    }

    // O^T += V^T @ P^T  (A-frag b64 from packed Vs; B-frag in registers)
#pragma unroll
    for (int nb = 0; nb < 4; ++nb)
#pragma unroll
      for (int db = 0; db < 4; ++db) {
        u32x2 raw = *(const u32x2*)&Vs[(db * 16 + c) * 34 + nb * 8 + 2 * g];
        f16x4 vf = __builtin_bit_cast(f16x4, raw);
#pragma unroll
        for (int st = 0; st < 2; ++st)
          acc_o[st][db] = mfma16(vf, pfrag[st][nb], acc_o[st][db]);
      }
    __syncthreads();
  }

  float inv[2] = {1.0f / l_i[0], 1.0f / l_i[1]};

  f16* Ot = (f16*)smem;  // [128][72]
#pragma unroll
  for (int st = 0; st < 2; ++st)
#pragma unroll
    for (int db = 0; db < 4; ++db)
#pragma unroll
      for (int r = 0; r < 4; ++r)
        Ot[(wave * 32 + st * 16 + c) * 72 + db * 16 + g * 4 + r] =
            (f16)(acc_o[st][db][r] * inv[st]);
  __syncthreads();
#pragma unroll
  for (int it = 0; it < 4; ++it) {
    int j = tid + it * 256;
    int row = j >> 3, ch = j & 7;
    *(f16x8*)&av[(size_t)((b0 + z) * 2048 + q0 + row) * 1024 + (gh0 + hh) * 64 + ch * 8] =
        *(const f16x8*)&Ot[row * 72 + ch * 8];
  }
}

__global__ __launch_bounds__(256) void copyk(const f16* __restrict__ src,
                                             f16* __restrict__ dst, long n8) {
  long i = (long)blockIdx.x * 256 + threadIdx.x;
  if (i < n8) ((f16x8*)dst)[i] = ((const f16x8*)src)[i];
}

// ---------------------------------------------------------------------------
extern "C" void kernel_launch(void* const* d_in, const int* in_sizes, int n_in,
                              void* d_out, int out_size, void* d_ws, size_t ws_size,
                              hipStream_t stream) {
  (void)in_sizes; (void)n_in; (void)out_size;
  const float* x    = (const float*)d_in[0];  // (4,2048,1024) fp32
  const float* Wqkv = (const float*)d_in[1];  // (48,1024,64)  fp32
  const float* bqkv = (const float*)d_in[2];  // (48,64)       fp32
  const float* Wp   = (const float*)d_in[3];  // (1024,1024)   fp32 [N][K]
  const float* bp   = (const float*)d_in[4];  // (1024,)       fp32
  float* out = (float*)d_out;                 // (4,2048,1024) fp32
  char* ws = (char*)d_ws;
  const size_t avail = ws_size;

  if (avail >= (size_t)67108864) {
    // ---- Tier A. d_out borrows: Wqkvt 6.29MB | biasc | xh 16.8MB (consumed
    // by gemm1). Wpf goes into the qkv ws region AFTER attn (qkv dead then).
    f16* Wqkvt = (f16*)d_out;
    f16* biasc = (f16*)((char*)d_out + 6291456);
    f16* xh    = (f16*)((char*)d_out + 6297600);
    f16* qkv = (f16*)ws;                    // 8192x3072 f16 (50.3MB)
    f16* av  = (f16*)(ws + 50331648);       // 8192x1024 f16 (16.8MB)
    f16* Wpf = (f16*)ws;                    // 1024x1024 f16 (2MB, aliases dead qkv)
    cvt_f16<<<dim3(4096), 256, 0, stream>>>(x, xh, 1048576);
    transpose_group<<<dim3(48, 16), 256, 0, stream>>>(Wqkv, bqkv, Wqkvt, biasc, 0, 16);
    gemm_bt<1, 1><<<dim3(24, 64), 256, 0, stream>>>(xh, 0, 0, Wqkvt, 0, biasc, 0,
                                                    qkv, 0, 1, 8192, 3072, 1024, 3072);
    attn_kernel<<<dim3(16, 16, 4), 256, 0, stream>>>(qkv, av, 3072, 1024, 2048, 0, 0);
    cvt_f16<<<dim3(512), 256, 0, stream>>>(Wp, Wpf, 131072);
    gemm_bt<1, 1><<<dim3(8, 64), 256, 0, stream>>>(av, 0, 0, Wpf, 0, bp, 1,
                                                   out, 0, 0, 8192, 1024, 1024, 1024);
    return;
  }

  // ---- Head-group tiers (legacy staging): av (f16) in d_out; projection
  // reverse-chunked (in-place safe under fp32 2x widening).
  auto need = [](size_t N, size_t Mr) { return N * 2 * (1024 + Mr + 1); };
  int G; bool perBatch = false;
  if      (avail >= need(3072, 8192)) G = 16;
  else if (avail >= need(1536, 8192)) G = 8;
  else if (avail >= need(768, 8192))  G = 4;
  else if (avail >= need(384, 8192))  G = 2;
  else if (avail >= need(256, 8192))  G = 1;
  else { G = 1; perBatch = true; }
  const int N = (G == 1) ? 256 : G * 192;
  const size_t Mr = perBatch ? 2048 : 8192;

  f16* Wt    = (f16*)ws;                                        // N x 1024
  f16* qkvg  = (f16*)(ws + (size_t)N * 1024 * 2);               // Mr x N
  f16* biasc = (f16*)(ws + (size_t)N * 1024 * 2 + Mr * N * 2);  // N
  f16* av    = (f16*)d_out;
  const int tgrid = 3 * G + (G == 1 ? 1 : 0);

  for (int g0 = 0; g0 < 16; g0 += G) {
    transpose_group<<<dim3(tgrid, 16), 256, 0, stream>>>(Wqkv, bqkv, Wt, biasc, g0, G);
    if (!perBatch) {
      gemm_bt<0, 0><<<dim3(N / 128, 64), 256, 0, stream>>>(x, 0, 1, Wt, 0, biasc, 0,
                                                           qkvg, 0, 1, 8192, N, 1024, N);
      attn_kernel<<<dim3(16, G, 4), 256, 0, stream>>>(qkvg, av, N, G * 64, 2 * G * 64, g0, 0);
    } else {
      for (int b = 0; b < 4; ++b) {
        gemm_bt<0, 0><<<dim3(N / 128, 16), 256, 0, stream>>>(x, (size_t)b * 2048 * 1024, 1,
                                                             Wt, 0, biasc, 0, qkvg, 0, 1,
                                                             2048, N, 1024, N);
        attn_kernel<<<dim3(16, G, 1), 256, 0, stream>>>(qkvg, av, N, G * 64, 2 * G * 64, g0, b);
      }
    }
  }

  f16* chunkbuf = qkvg;
  const int rows = perBatch ? 512 : 1024;
  for (int r0 = 8192 - rows; r0 >= 0; r0 -= rows) {
    long n8 = (long)rows * 1024 / 8;
    copyk<<<dim3((int)(n8 / 256)), 256, 0, stream>>>(av + (size_t)r0 * 1024, chunkbuf, n8);
    gemm_bt<0, 0><<<dim3(8, rows / 128), 256, 0, stream>>>(chunkbuf, 0, 0, Wp, 1, bp, 1,
                                                           out, (size_t)r0 * 1024, 0,
                                                           rows, 1024, 1024, 1024);
  }
}